// Round 1
// baseline (1790.629 us; speedup 1.0000x reference)
//
#include <hip/hip_runtime.h>
#include <hip/hip_bf16.h>
#include <math.h>

#define D_ 1024
#define H_ 16
#define F_ 4096
#define S_ 1024
#define B_ 2
#define MTOT 2048   // B_*S_

using bf16 = __hip_bfloat16;
typedef __bf16 bf16x8 __attribute__((ext_vector_type(8)));
typedef float f32x4 __attribute__((ext_vector_type(4)));

__device__ __forceinline__ void gload_lds16(const void* g, void* l) {
  __builtin_amdgcn_global_load_lds((const __attribute__((address_space(1))) void*)g,
                                   (__attribute__((address_space(3))) void*)l, 16, 0, 0);
}

__device__ __forceinline__ unsigned short f2b(float f) {
  union { bf16 h; unsigned short u; } c;
  c.h = __float2bfloat16(f);
  return c.u;
}

// ---------------- embedding: x = emb[id]*sqrt(D) + pos ----------------
__global__ __launch_bounds__(256) void embed_kernel(const int* __restrict__ ids,
    const float* __restrict__ emb, const float* __restrict__ pos, float* __restrict__ x) {
  int row = blockIdx.x;              // 0..2047 = b*S + s
  int s = row & (S_ - 1);
  int id = ids[row];
  const float4* e = (const float4*)(emb + (size_t)id * D_);
  const float4* p = (const float4*)(pos + (size_t)s * D_);
  float4* xo = (float4*)(x + (size_t)row * D_);
  int t = threadIdx.x;               // 256 threads * 4 floats = 1024
  float4 ev = e[t], pv = p[t], r;
  r.x = ev.x * 32.0f + pv.x; r.y = ev.y * 32.0f + pv.y;
  r.z = ev.z * 32.0f + pv.z; r.w = ev.w * 32.0f + pv.w;
  xo[t] = r;
}

// ---------------- layernorm (f32 in) -> bf16 out ----------------
__global__ __launch_bounds__(256) void ln_kernel(const float* __restrict__ x,
    const float* __restrict__ w, const float* __restrict__ b, bf16* __restrict__ h) {
  int row = blockIdx.x, t = threadIdx.x;
  const float4* xr = (const float4*)(x + (size_t)row * D_);
  float4 v = xr[t];
  float s = v.x + v.y + v.z + v.w;
  float s2 = v.x * v.x + v.y * v.y + v.z * v.z + v.w * v.w;
  #pragma unroll
  for (int o = 32; o; o >>= 1) { s += __shfl_down(s, o); s2 += __shfl_down(s2, o); }
  __shared__ float red[8];
  int wave = t >> 6, lane = t & 63;
  if (lane == 0) { red[wave] = s; red[4 + wave] = s2; }
  __syncthreads();
  float mean = (red[0] + red[1] + red[2] + red[3]) * (1.0f / D_);
  float m2   = (red[4] + red[5] + red[6] + red[7]) * (1.0f / D_);
  float rstd = rsqrtf(m2 - mean * mean + 1e-5f);
  float4 wv = ((const float4*)w)[t], bv = ((const float4*)b)[t];
  ushort4 o4;
  o4.x = f2b((v.x - mean) * rstd * wv.x + bv.x);
  o4.y = f2b((v.y - mean) * rstd * wv.y + bv.y);
  o4.z = f2b((v.z - mean) * rstd * wv.z + bv.z);
  o4.w = f2b((v.w - mean) * rstd * wv.w + bv.w);
  ((ushort4*)(h + (size_t)row * D_))[t] = o4;
}

// ---------------- per-layer weight conversion f32 -> bf16 ----------------
// wbuf layout: [qw 1M | kw 1M | vw 1M | ow 1M | w1 4M | w2 4M] elements
__global__ __launch_bounds__(256) void cvt6_kernel(const float4* __restrict__ s0,
    const float4* __restrict__ s1, const float4* __restrict__ s2, const float4* __restrict__ s3,
    const float4* __restrict__ s4, const float4* __restrict__ s5, ushort4* __restrict__ dst) {
  int i = blockIdx.x * 256 + threadIdx.x;   // 0 .. 3145727 (float4 units)
  const float4* src; int off;
  if (i < 1048576) {
    int seg = i >> 18; off = i & 262143;
    src = seg == 0 ? s0 : seg == 1 ? s1 : seg == 2 ? s2 : s3;
  } else if (i < 2097152) { src = s4; off = i - 1048576; }
  else                    { src = s5; off = i - 2097152; }
  float4 v = src[off];
  ushort4 r;
  r.x = f2b(v.x); r.y = f2b(v.y); r.z = f2b(v.z); r.w = f2b(v.w);
  dst[i] = r;
}

// ---------------- GEMM: C[M,N] = A[M,K] @ B[N,K]^T (+bias, epilogue by MODE) ---
// MODE 0: fused QKV, N=3072: seg0->q bf16[M][1024], seg1->k, seg2->vT[B,H*DH][S]
// MODE 1: residual f32: x[m*N+n] += acc + bias[n]
// MODE 2: gelu -> bf16 out[m*N+n]
template<int MODE>
__global__ __launch_bounds__(256) void gemm_bt(const bf16* __restrict__ A,
    const bf16* __restrict__ Bw,
    const float* __restrict__ b0_, const float* __restrict__ b1_, const float* __restrict__ b2_,
    void* __restrict__ o0, void* __restrict__ o1, void* __restrict__ o2,
    int M, int N, int K) {
  __shared__ alignas(16) bf16 As[128 * 32];
  __shared__ alignas(16) bf16 Bs[128 * 32];
  int tid = threadIdx.x, wave = tid >> 6, lane = tid & 63;
  int m0 = blockIdx.y * 128, n0 = blockIdx.x * 128;
  int wr = wave >> 1, wc = wave & 1;
  int lr = lane & 15, lg = lane >> 4;
  f32x4 acc[4][4] = {};
  for (int k0 = 0; k0 < K; k0 += 32) {
    __syncthreads();   // all waves done reading previous tile
    #pragma unroll
    for (int j = 0; j < 2; j++) {
      int cidx = (wave * 2 + j) * 64 + lane;   // 16B chunk index 0..511
      int row = cidx >> 2, c8 = cidx & 3;
      gload_lds16(A  + (size_t)(m0 + row) * K + k0 + c8 * 8, As + (wave * 2 + j) * 512);
      gload_lds16(Bw + (size_t)(n0 + row) * K + k0 + c8 * 8, Bs + (wave * 2 + j) * 512);
    }
    __syncthreads();   // compiler drains vmcnt before barrier
    bf16x8 af[4], bf_[4];
    #pragma unroll
    for (int f = 0; f < 4; f++) {
      af[f]  = *(const bf16x8*)&As[(wr * 64 + f * 16 + lr) * 32 + lg * 8];
      bf_[f] = *(const bf16x8*)&Bs[(wc * 64 + f * 16 + lr) * 32 + lg * 8];
    }
    #pragma unroll
    for (int mf = 0; mf < 4; mf++)
      #pragma unroll
      for (int nf = 0; nf < 4; nf++)
        acc[mf][nf] = __builtin_amdgcn_mfma_f32_16x16x32_bf16(af[mf], bf_[nf], acc[mf][nf], 0, 0, 0);
  }
  // epilogue: lane element (mf,nf,i): row m, col n
  #pragma unroll
  for (int mf = 0; mf < 4; mf++) {
    #pragma unroll
    for (int nf = 0; nf < 4; nf++) {
      int n = n0 + wc * 64 + nf * 16 + lr;
      #pragma unroll
      for (int i = 0; i < 4; i++) {
        int m = m0 + wr * 64 + mf * 16 + lg * 4 + i;
        float v = acc[mf][nf][i];
        if (MODE == 0) {
          int seg = n >> 10, nl = n & 1023;
          if (seg == 0)      ((bf16*)o0)[(size_t)m * 1024 + nl] = __float2bfloat16(v + b0_[nl]);
          else if (seg == 1) ((bf16*)o1)[(size_t)m * 1024 + nl] = __float2bfloat16(v + b1_[nl]);
          else {
            int bb = m >> 10, s = m & 1023;   // vT[(b*D + nl)][s]
            ((bf16*)o2)[((size_t)(bb * 1024 + nl)) * 1024 + s] = __float2bfloat16(v + b2_[nl]);
          }
        } else if (MODE == 1) {
          float* xp = (float*)o0;
          xp[(size_t)m * N + n] += v + b0_[n];
        } else {
          float g = v + b0_[n];
          float t = tanhf(0.7978845608028654f * (g + 0.044715f * g * g * g));
          ((bf16*)o0)[(size_t)m * N + n] = __float2bfloat16(0.5f * g * (1.0f + t));
        }
      }
    }
  }
}

// ---------------- fused attention: one (b,h) x 16 q-rows per block ----------
// q,k: bf16 [B*S][D] (head-sliced), vT: bf16 [(b*D + h*64 + d)][S], o: bf16 [B*S][D]
__global__ __launch_bounds__(256) void attn_kernel(const bf16* __restrict__ qbuf,
    const bf16* __restrict__ kbuf, const bf16* __restrict__ vT, bf16* __restrict__ obuf) {
  int bh = blockIdx.y;                 // 0..31
  int b = bh >> 4, h = bh & 15;
  int q0 = blockIdx.x * 16;
  int tid = threadIdx.x, wave = tid >> 6, lane = tid & 63;
  int lr = lane & 15, lg = lane >> 4;

  __shared__ alignas(16) bf16 P[16][1032];   // padded: stride 2064B == 4 words mod 32
  __shared__ float red[4][16];

  // Q fragments (A operand), rows q0..q0+15, K-dim 64 = 2 MFMA k-steps
  const bf16* qp = qbuf + ((size_t)(b * S_ + q0)) * D_ + h * 64;
  bf16x8 aq[2];
  aq[0] = *(const bf16x8*)(qp + (size_t)lr * D_ + lg * 8);
  aq[1] = *(const bf16x8*)(qp + (size_t)lr * D_ + 32 + lg * 8);

  // QK^T: wave handles key strip [wave*256, wave*256+256)
  const bf16* kb_ = kbuf + ((size_t)(b * S_)) * D_ + h * 64;
  int nbase = wave * 256;
  f32x4 acc[16] = {};
  #pragma unroll
  for (int nf = 0; nf < 16; nf++) {
    const bf16* kp = kb_ + (size_t)(nbase + nf * 16 + lr) * D_ + lg * 8;
    bf16x8 bk0 = *(const bf16x8*)(kp);
    bf16x8 bk1 = *(const bf16x8*)(kp + 32);
    acc[nf] = __builtin_amdgcn_mfma_f32_16x16x32_bf16(aq[0], bk0, acc[nf], 0, 0, 0);
    acc[nf] = __builtin_amdgcn_mfma_f32_16x16x32_bf16(aq[1], bk1, acc[nf], 0, 0, 0);
  }

  // per-row max within wave (rows lg*4+i, cols lr + 16*nf)
  float pm[4];
  #pragma unroll
  for (int i = 0; i < 4; i++) {
    float m = acc[0][i];
    #pragma unroll
    for (int nf = 1; nf < 16; nf++) m = fmaxf(m, acc[nf][i]);
    pm[i] = m;
  }
  #pragma unroll
  for (int msk = 1; msk < 16; msk <<= 1)
    #pragma unroll
    for (int i = 0; i < 4; i++) pm[i] = fmaxf(pm[i], __shfl_xor(pm[i], msk));
  if (lr == 0)
    #pragma unroll
    for (int i = 0; i < 4; i++) red[wave][lg * 4 + i] = pm[i];
  __syncthreads();

  float gm[4];
  #pragma unroll
  for (int i = 0; i < 4; i++) {
    int r = lg * 4 + i;
    gm[i] = fmaxf(fmaxf(red[0][r], red[1][r]), fmaxf(red[2][r], red[3][r]));
  }

  // p = exp((s - max)/8), unnormalized; write P bf16; accumulate row sums
  float ps[4] = {0.f, 0.f, 0.f, 0.f};
  #pragma unroll
  for (int nf = 0; nf < 16; nf++)
    #pragma unroll
    for (int i = 0; i < 4; i++) {
      float p = __expf((acc[nf][i] - gm[i]) * 0.125f);
      ps[i] += p;
      P[lg * 4 + i][nbase + nf * 16 + lr] = __float2bfloat16(p);
    }
  #pragma unroll
  for (int msk = 1; msk < 16; msk <<= 1)
    #pragma unroll
    for (int i = 0; i < 4; i++) ps[i] += __shfl_xor(ps[i], msk);
  __syncthreads();                      // gm reads done -> red reusable
  if (lr == 0)
    #pragma unroll
    for (int i = 0; i < 4; i++) red[wave][lg * 4 + i] = ps[i];
  __syncthreads();
  float rs[4];
  #pragma unroll
  for (int i = 0; i < 4; i++) {
    int r = lg * 4 + i;
    rs[i] = red[0][r] + red[1][r] + red[2][r] + red[3][r];
  }

  // PV: o[16 rows][64 dims], wave owns dims [wave*16, wave*16+16)
  const bf16* vp = vT + ((size_t)(b * D_ + h * 64 + wave * 16 + lr)) * S_ + lg * 8;
  f32x4 oacc = {};
  #pragma unroll 8
  for (int k0 = 0; k0 < S_; k0 += 32) {
    bf16x8 pa = *(const bf16x8*)&P[lr][k0 + lg * 8];
    bf16x8 bv = *(const bf16x8*)(vp + k0);
    oacc = __builtin_amdgcn_mfma_f32_16x16x32_bf16(pa, bv, oacc, 0, 0, 0);
  }
  #pragma unroll
  for (int i = 0; i < 4; i++) {
    int r = lg * 4 + i;
    obuf[((size_t)(b * S_ + q0 + r)) * D_ + h * 64 + wave * 16 + lr] =
        __float2bfloat16(oacc[i] / rs[i]);
  }
}

// ---------------- host launch ----------------
extern "C" void kernel_launch(void* const* d_in, const int* in_sizes, int n_in,
                              void* d_out, int out_size, void* d_ws, size_t ws_size,
                              hipStream_t stream) {
  const int*   ids  = (const int*)d_in[0];
  // d_in[1] = attention_mask (all true) -- unused
  const float* emb  = (const float*)d_in[2];
  const float* pos  = (const float*)d_in[3];
  const float* ln1w = (const float*)d_in[4];
  const float* ln1b = (const float*)d_in[5];
  const float* qw = (const float*)d_in[6];  const float* qb = (const float*)d_in[7];
  const float* kw = (const float*)d_in[8];  const float* kb = (const float*)d_in[9];
  const float* vw = (const float*)d_in[10]; const float* vb = (const float*)d_in[11];
  const float* ow = (const float*)d_in[12]; const float* ob = (const float*)d_in[13];
  const float* ln2w = (const float*)d_in[14]; const float* ln2b = (const float*)d_in[15];
  const float* w1 = (const float*)d_in[16]; const float* b1 = (const float*)d_in[17];
  const float* w2 = (const float*)d_in[18]; const float* b2 = (const float*)d_in[19];
  (void)in_sizes; (void)n_in; (void)out_size; (void)ws_size;

  float* x = (float*)d_out;            // residual stream lives in d_out (f32 [2048][1024])
  char* ws = (char*)d_ws;
  const size_t SZ_ACT = (size_t)MTOT * D_ * 2;       // 4 MB bf16
  bf16* h    = (bf16*)(ws);
  bf16* q    = (bf16*)(ws + SZ_ACT);
  bf16* k    = (bf16*)(ws + 2 * SZ_ACT);
  bf16* vt   = (bf16*)(ws + 3 * SZ_ACT);
  bf16* o    = (bf16*)(ws + 4 * SZ_ACT);
  bf16* mid  = (bf16*)(ws + 5 * SZ_ACT);             // 16 MB
  bf16* wbuf = (bf16*)(ws + 5 * SZ_ACT + (size_t)MTOT * F_ * 2);  // 25.2 MB

  const size_t DD = (size_t)D_ * D_;       // 1048576
  const size_t FD = (size_t)F_ * D_;       // 4194304

  embed_kernel<<<MTOT, 256, 0, stream>>>(ids, emb, pos, x);

  for (int l = 0; l < 6; l++) {
    cvt6_kernel<<<12288, 256, 0, stream>>>(
        (const float4*)(qw + l * DD), (const float4*)(kw + l * DD),
        (const float4*)(vw + l * DD), (const float4*)(ow + l * DD),
        (const float4*)(w1 + l * FD), (const float4*)(w2 + l * FD),
        (ushort4*)wbuf);

    ln_kernel<<<MTOT, 256, 0, stream>>>(x, ln1w + l * D_, ln1b + l * D_, h);

    // fused QKV: N = 3072
    gemm_bt<0><<<dim3(24, 16), 256, 0, stream>>>(h, wbuf,
        qb + l * D_, kb + l * D_, vb + l * D_, q, k, vt, MTOT, 3072, 1024);

    attn_kernel<<<dim3(64, 32), 256, 0, stream>>>(q, k, vt, o);

    // x += o @ ow^T + ob
    gemm_bt<1><<<dim3(8, 16), 256, 0, stream>>>(o, wbuf + 3 * DD,
        ob + l * D_, nullptr, nullptr, x, nullptr, nullptr, MTOT, 1024, 1024);

    ln_kernel<<<MTOT, 256, 0, stream>>>(x, ln2w + l * D_, ln2b + l * D_, h);

    // mid = gelu(h @ w1^T + b1)
    gemm_bt<2><<<dim3(32, 16), 256, 0, stream>>>(h, wbuf + 4 * DD,
        b1 + l * F_, nullptr, nullptr, mid, nullptr, nullptr, MTOT, 4096, 1024);

    // x += mid @ w2^T + b2
    gemm_bt<1><<<dim3(8, 16), 256, 0, stream>>>(mid, wbuf + 4 * DD + FD,
        b2 + l * D_, nullptr, nullptr, x, nullptr, nullptr, MTOT, 1024, 4096);
  }
}

// Round 2
// 1237.383 us; speedup vs baseline: 1.4471x; 1.4471x over previous
//
#include <hip/hip_runtime.h>
#include <hip/hip_bf16.h>
#include <math.h>

#define D_ 1024
#define H_ 16
#define F_ 4096
#define S_ 1024
#define B_ 2
#define MTOT 2048   // B_*S_

using bf16 = __hip_bfloat16;
typedef __bf16 bf16x8 __attribute__((ext_vector_type(8)));
typedef float f32x4 __attribute__((ext_vector_type(4)));

__device__ __forceinline__ void gload_lds16(const void* g, void* l) {
  __builtin_amdgcn_global_load_lds((const __attribute__((address_space(1))) void*)g,
                                   (__attribute__((address_space(3))) void*)l, 16, 0, 0);
}

__device__ __forceinline__ unsigned short f2b(float f) {
  union { bf16 h; unsigned short u; } c;
  c.h = __float2bfloat16(f);
  return c.u;
}

// ---------------- embedding: x = emb[id]*sqrt(D) + pos ----------------
__global__ __launch_bounds__(256) void embed_kernel(const int* __restrict__ ids,
    const float* __restrict__ emb, const float* __restrict__ pos, float* __restrict__ x) {
  int row = blockIdx.x;              // 0..2047 = b*S + s
  int s = row & (S_ - 1);
  int id = ids[row];
  const float4* e = (const float4*)(emb + (size_t)id * D_);
  const float4* p = (const float4*)(pos + (size_t)s * D_);
  float4* xo = (float4*)(x + (size_t)row * D_);
  int t = threadIdx.x;               // 256 threads * 4 floats = 1024
  float4 ev = e[t], pv = p[t], r;
  r.x = ev.x * 32.0f + pv.x; r.y = ev.y * 32.0f + pv.y;
  r.z = ev.z * 32.0f + pv.z; r.w = ev.w * 32.0f + pv.w;
  xo[t] = r;
}

// ---------------- layernorm (f32 in) -> bf16 out ----------------
__global__ __launch_bounds__(256) void ln_kernel(const float* __restrict__ x,
    const float* __restrict__ w, const float* __restrict__ b, bf16* __restrict__ h) {
  int row = blockIdx.x, t = threadIdx.x;
  const float4* xr = (const float4*)(x + (size_t)row * D_);
  float4 v = xr[t];
  float s = v.x + v.y + v.z + v.w;
  float s2 = v.x * v.x + v.y * v.y + v.z * v.z + v.w * v.w;
  #pragma unroll
  for (int o = 32; o; o >>= 1) { s += __shfl_down(s, o); s2 += __shfl_down(s2, o); }
  __shared__ float red[8];
  int wave = t >> 6, lane = t & 63;
  if (lane == 0) { red[wave] = s; red[4 + wave] = s2; }
  __syncthreads();
  float mean = (red[0] + red[1] + red[2] + red[3]) * (1.0f / D_);
  float m2   = (red[4] + red[5] + red[6] + red[7]) * (1.0f / D_);
  float rstd = rsqrtf(m2 - mean * mean + 1e-5f);
  float4 wv = ((const float4*)w)[t], bv = ((const float4*)b)[t];
  ushort4 o4;
  o4.x = f2b((v.x - mean) * rstd * wv.x + bv.x);
  o4.y = f2b((v.y - mean) * rstd * wv.y + bv.y);
  o4.z = f2b((v.z - mean) * rstd * wv.z + bv.z);
  o4.w = f2b((v.w - mean) * rstd * wv.w + bv.w);
  ((ushort4*)(h + (size_t)row * D_))[t] = o4;
}

// ---------------- per-layer weight conversion f32 -> bf16 ----------------
// wbuf layout: [qw 1M | kw 1M | vw 1M | ow 1M | w1 4M | w2 4M] elements
__global__ __launch_bounds__(256) void cvt6_kernel(const float4* __restrict__ s0,
    const float4* __restrict__ s1, const float4* __restrict__ s2, const float4* __restrict__ s3,
    const float4* __restrict__ s4, const float4* __restrict__ s5, ushort4* __restrict__ dst) {
  int i = blockIdx.x * 256 + threadIdx.x;   // 0 .. 3145727 (float4 units)
  const float4* src; int off;
  if (i < 1048576) {
    int seg = i >> 18; off = i & 262143;
    src = seg == 0 ? s0 : seg == 1 ? s1 : seg == 2 ? s2 : s3;
  } else if (i < 2097152) { src = s4; off = i - 1048576; }
  else                    { src = s5; off = i - 2097152; }
  float4 v = src[off];
  ushort4 r;
  r.x = f2b(v.x); r.y = f2b(v.y); r.z = f2b(v.z); r.w = f2b(v.w);
  dst[i] = r;
}

// ---------------- GEMM: C[M,N] = A[M,K] @ B[N,K]^T (+bias, epilogue by MODE) ---
// 128x128 tile, BK=64, double-buffered LDS, XOR chunk swizzle (both sides).
// MODE 0: fused QKV, N=3072: seg0->q bf16[M][1024], seg1->k, seg2->vT[B,H*DH][S]
// MODE 1: residual f32 (atomicAdd, supports split-K over blockIdx.z)
// MODE 2: gelu -> bf16 out[m*N+n]
template<int MODE>
__global__ __launch_bounds__(256) void gemm_bt(const bf16* __restrict__ A,
    const bf16* __restrict__ Bw,
    const float* __restrict__ b0_, const float* __restrict__ b1_, const float* __restrict__ b2_,
    void* __restrict__ o0, void* __restrict__ o1, void* __restrict__ o2,
    int M, int N, int K, int kspl) {
  __shared__ alignas(16) bf16 As[2][128 * 64];
  __shared__ alignas(16) bf16 Bs[2][128 * 64];
  int tid = threadIdx.x, wave = tid >> 6, lane = tid & 63;
  // XCD-aware linear-block swizzle (all grids are %8 == 0)
  int nbn = N >> 7;
  int nwg = gridDim.x;
  int bid = blockIdx.x;
  int swz = (bid & 7) * (nwg >> 3) + (bid >> 3);
  int bm = swz / nbn, bn = swz % nbn;
  int m0 = bm << 7, n0 = bn << 7;
  int kbase = blockIdx.z * kspl;
  int wr = wave >> 1, wc = wave & 1;
  int lr = lane & 15, lg = lane >> 4;

  // stage one 128x64 A-tile + B-tile into buffer `buf` at global k-offset k0.
  // LDS row r (128 B = 8 chunks of 16B): slot s holds data chunk s ^ (r&7).
  auto stage = [&](int buf, int k0) {
    #pragma unroll
    for (int j = 0; j < 4; j++) {
      int cidx = j * 256 + tid;          // chunk 0..1023
      int r = cidx >> 3, s = cidx & 7;
      int g = s ^ (r & 7);
      // wave-uniform LDS base + lane*16 written by HW
      bf16* abase = &As[buf][(j * 256 + wave * 64) * 8];
      bf16* bbase = &Bs[buf][(j * 256 + wave * 64) * 8];
      gload_lds16(A  + (size_t)(m0 + r) * K + k0 + g * 8, abase);
      gload_lds16(Bw + (size_t)(n0 + r) * K + k0 + g * 8, bbase);
    }
  };

  f32x4 acc[4][4] = {};
  int nk = kspl >> 6;
  stage(0, kbase);
  __syncthreads();
  int cur = 0;
  for (int t = 0; t < nk; ++t) {
    if (t + 1 < nk) stage(cur ^ 1, kbase + (t + 1) * 64);
    __builtin_amdgcn_s_setprio(1);
    #pragma unroll
    for (int kk = 0; kk < 2; ++kk) {
      bf16x8 af[4], bfr[4];
      #pragma unroll
      for (int f = 0; f < 4; f++) {
        int ra = wr * 64 + f * 16 + lr;
        int rb = wc * 64 + f * 16 + lr;
        af[f]  = *(const bf16x8*)&As[cur][ra * 64 + (((kk * 4 + lg) ^ (ra & 7)) * 8)];
        bfr[f] = *(const bf16x8*)&Bs[cur][rb * 64 + (((kk * 4 + lg) ^ (rb & 7)) * 8)];
      }
      #pragma unroll
      for (int mf = 0; mf < 4; mf++)
        #pragma unroll
        for (int nf = 0; nf < 4; nf++)
          acc[mf][nf] = __builtin_amdgcn_mfma_f32_16x16x32_bf16(af[mf], bfr[nf], acc[mf][nf], 0, 0, 0);
    }
    __builtin_amdgcn_s_setprio(0);
    __syncthreads();   // drains vmcnt (stage issued at top had full compute phase to land)
    cur ^= 1;
  }

  // epilogue: lane element (mf,nf,i): row m = m0+wr*64+mf*16+lg*4+i, col n
  #pragma unroll
  for (int mf = 0; mf < 4; mf++) {
    #pragma unroll
    for (int nf = 0; nf < 4; nf++) {
      int n = n0 + wc * 64 + nf * 16 + lr;
      if (MODE == 0 && n >= 2048) {
        // V head-transposed: vT[(b*D + nl)][s], s = m. Pack 4 consecutive s.
        int nl = n & 1023;
        int mbase = m0 + wr * 64 + mf * 16 + lg * 4;
        int bb = mbase >> 10, sb = mbase & 1023;
        float bias = b2_[nl];
        ushort4 pk;
        pk.x = f2b(acc[mf][nf][0] + bias);
        pk.y = f2b(acc[mf][nf][1] + bias);
        pk.z = f2b(acc[mf][nf][2] + bias);
        pk.w = f2b(acc[mf][nf][3] + bias);
        *(ushort4*)&((bf16*)o2)[((size_t)(bb * 1024 + nl)) * 1024 + sb] = pk;
      } else {
        #pragma unroll
        for (int i = 0; i < 4; i++) {
          int m = m0 + wr * 64 + mf * 16 + lg * 4 + i;
          float v = acc[mf][nf][i];
          if (MODE == 0) {
            int seg = n >> 10, nl = n & 1023;
            if (seg == 0)      ((bf16*)o0)[(size_t)m * 1024 + nl] = __float2bfloat16(v + b0_[nl]);
            else               ((bf16*)o1)[(size_t)m * 1024 + nl] = __float2bfloat16(v + b1_[nl]);
          } else if (MODE == 1) {
            float bias = (blockIdx.z == 0) ? b0_[n] : 0.0f;
            atomicAdd(&((float*)o0)[(size_t)m * N + n], v + bias);
          } else {
            float g = v + b0_[n];
            float t = tanhf(0.7978845608028654f * (g + 0.044715f * g * g * g));
            ((bf16*)o0)[(size_t)m * N + n] = __float2bfloat16(0.5f * g * (1.0f + t));
          }
        }
      }
    }
  }
}

// ---------------- fused attention: one (b,h) x 16 q-rows per block ----------
// q,k: bf16 [B*S][D] (head-sliced), vT: bf16 [(b*D + h*64 + d)][S], o: bf16 [B*S][D]
__global__ __launch_bounds__(256) void attn_kernel(const bf16* __restrict__ qbuf,
    const bf16* __restrict__ kbuf, const bf16* __restrict__ vT, bf16* __restrict__ obuf) {
  int bh = blockIdx.y;                 // 0..31
  int b = bh >> 4, h = bh & 15;
  int q0 = blockIdx.x * 16;
  int tid = threadIdx.x, wave = tid >> 6, lane = tid & 63;
  int lr = lane & 15, lg = lane >> 4;

  __shared__ alignas(16) bf16 P[16][1032];   // padded: stride 2064B == 4 words mod 32
  __shared__ float red[4][16];

  // Q fragments (A operand), rows q0..q0+15, K-dim 64 = 2 MFMA k-steps
  const bf16* qp = qbuf + ((size_t)(b * S_ + q0)) * D_ + h * 64;
  bf16x8 aq[2];
  aq[0] = *(const bf16x8*)(qp + (size_t)lr * D_ + lg * 8);
  aq[1] = *(const bf16x8*)(qp + (size_t)lr * D_ + 32 + lg * 8);

  // QK^T: wave handles key strip [wave*256, wave*256+256)
  const bf16* kb_ = kbuf + ((size_t)(b * S_)) * D_ + h * 64;
  int nbase = wave * 256;
  f32x4 acc[16] = {};
  #pragma unroll
  for (int nf = 0; nf < 16; nf++) {
    const bf16* kp = kb_ + (size_t)(nbase + nf * 16 + lr) * D_ + lg * 8;
    bf16x8 bk0 = *(const bf16x8*)(kp);
    bf16x8 bk1 = *(const bf16x8*)(kp + 32);
    acc[nf] = __builtin_amdgcn_mfma_f32_16x16x32_bf16(aq[0], bk0, acc[nf], 0, 0, 0);
    acc[nf] = __builtin_amdgcn_mfma_f32_16x16x32_bf16(aq[1], bk1, acc[nf], 0, 0, 0);
  }

  // per-row max within wave (rows lg*4+i, cols lr + 16*nf)
  float pm[4];
  #pragma unroll
  for (int i = 0; i < 4; i++) {
    float m = acc[0][i];
    #pragma unroll
    for (int nf = 1; nf < 16; nf++) m = fmaxf(m, acc[nf][i]);
    pm[i] = m;
  }
  #pragma unroll
  for (int msk = 1; msk < 16; msk <<= 1)
    #pragma unroll
    for (int i = 0; i < 4; i++) pm[i] = fmaxf(pm[i], __shfl_xor(pm[i], msk));
  if (lr == 0)
    #pragma unroll
    for (int i = 0; i < 4; i++) red[wave][lg * 4 + i] = pm[i];
  __syncthreads();

  float gm[4];
  #pragma unroll
  for (int i = 0; i < 4; i++) {
    int r = lg * 4 + i;
    gm[i] = fmaxf(fmaxf(red[0][r], red[1][r]), fmaxf(red[2][r], red[3][r]));
  }

  // p = exp((s - max)/8), unnormalized; write P bf16; accumulate row sums
  float ps[4] = {0.f, 0.f, 0.f, 0.f};
  #pragma unroll
  for (int nf = 0; nf < 16; nf++)
    #pragma unroll
    for (int i = 0; i < 4; i++) {
      float p = __expf((acc[nf][i] - gm[i]) * 0.125f);
      ps[i] += p;
      P[lg * 4 + i][nbase + nf * 16 + lr] = __float2bfloat16(p);
    }
  #pragma unroll
  for (int msk = 1; msk < 16; msk <<= 1)
    #pragma unroll
    for (int i = 0; i < 4; i++) ps[i] += __shfl_xor(ps[i], msk);
  __syncthreads();                      // gm reads done -> red reusable
  if (lr == 0)
    #pragma unroll
    for (int i = 0; i < 4; i++) red[wave][lg * 4 + i] = ps[i];
  __syncthreads();
  float rs[4];
  #pragma unroll
  for (int i = 0; i < 4; i++) {
    int r = lg * 4 + i;
    rs[i] = red[0][r] + red[1][r] + red[2][r] + red[3][r];
  }

  // PV: o[16 rows][64 dims], wave owns dims [wave*16, wave*16+16)
  const bf16* vp = vT + ((size_t)(b * D_ + h * 64 + wave * 16 + lr)) * S_ + lg * 8;
  f32x4 oacc = {};
  #pragma unroll 8
  for (int k0 = 0; k0 < S_; k0 += 32) {
    bf16x8 pa = *(const bf16x8*)&P[lr][k0 + lg * 8];
    bf16x8 bv = *(const bf16x8*)(vp + k0);
    oacc = __builtin_amdgcn_mfma_f32_16x16x32_bf16(pa, bv, oacc, 0, 0, 0);
  }
  #pragma unroll
  for (int i = 0; i < 4; i++) {
    int r = lg * 4 + i;
    obuf[((size_t)(b * S_ + q0 + r)) * D_ + h * 64 + wave * 16 + lr] =
        __float2bfloat16(oacc[i] / rs[i]);
  }
}

// ---------------- host launch ----------------
extern "C" void kernel_launch(void* const* d_in, const int* in_sizes, int n_in,
                              void* d_out, int out_size, void* d_ws, size_t ws_size,
                              hipStream_t stream) {
  const int*   ids  = (const int*)d_in[0];
  // d_in[1] = attention_mask (all true) -- unused
  const float* emb  = (const float*)d_in[2];
  const float* pos  = (const float*)d_in[3];
  const float* ln1w = (const float*)d_in[4];
  const float* ln1b = (const float*)d_in[5];
  const float* qw = (const float*)d_in[6];  const float* qb = (const float*)d_in[7];
  const float* kw = (const float*)d_in[8];  const float* kb = (const float*)d_in[9];
  const float* vw = (const float*)d_in[10]; const float* vb = (const float*)d_in[11];
  const float* ow = (const float*)d_in[12]; const float* ob = (const float*)d_in[13];
  const float* ln2w = (const float*)d_in[14]; const float* ln2b = (const float*)d_in[15];
  const float* w1 = (const float*)d_in[16]; const float* b1 = (const float*)d_in[17];
  const float* w2 = (const float*)d_in[18]; const float* b2 = (const float*)d_in[19];
  (void)in_sizes; (void)n_in; (void)out_size; (void)ws_size;

  float* x = (float*)d_out;            // residual stream lives in d_out (f32 [2048][1024])
  char* ws = (char*)d_ws;
  const size_t SZ_ACT = (size_t)MTOT * D_ * 2;       // 4 MB bf16
  bf16* h    = (bf16*)(ws);
  bf16* q    = (bf16*)(ws + SZ_ACT);
  bf16* k    = (bf16*)(ws + 2 * SZ_ACT);
  bf16* vt   = (bf16*)(ws + 3 * SZ_ACT);
  bf16* o    = (bf16*)(ws + 4 * SZ_ACT);
  bf16* mid  = (bf16*)(ws + 5 * SZ_ACT);             // 16 MB
  bf16* wbuf = (bf16*)(ws + 5 * SZ_ACT + (size_t)MTOT * F_ * 2);  // 25.2 MB

  const size_t DD = (size_t)D_ * D_;       // 1048576
  const size_t FD = (size_t)F_ * D_;       // 4194304

  embed_kernel<<<MTOT, 256, 0, stream>>>(ids, emb, pos, x);

  for (int l = 0; l < 6; l++) {
    cvt6_kernel<<<12288, 256, 0, stream>>>(
        (const float4*)(qw + l * DD), (const float4*)(kw + l * DD),
        (const float4*)(vw + l * DD), (const float4*)(ow + l * DD),
        (const float4*)(w1 + l * FD), (const float4*)(w2 + l * FD),
        (ushort4*)wbuf);

    ln_kernel<<<MTOT, 256, 0, stream>>>(x, ln1w + l * D_, ln1b + l * D_, h);

    // fused QKV: N = 3072, 384 blocks
    gemm_bt<0><<<dim3(384, 1, 1), 256, 0, stream>>>(h, wbuf,
        qb + l * D_, kb + l * D_, vb + l * D_, q, k, vt, MTOT, 3072, 1024, 1024);

    attn_kernel<<<dim3(64, 32), 256, 0, stream>>>(q, k, vt, o);

    // x += o @ ow^T + ob   (split-K=2 -> 256 blocks)
    gemm_bt<1><<<dim3(128, 1, 2), 256, 0, stream>>>(o, wbuf + 3 * DD,
        ob + l * D_, nullptr, nullptr, x, nullptr, nullptr, MTOT, 1024, 1024, 512);

    ln_kernel<<<MTOT, 256, 0, stream>>>(x, ln2w + l * D_, ln2b + l * D_, h);

    // mid = gelu(h @ w1^T + b1), 512 blocks
    gemm_bt<2><<<dim3(512, 1, 1), 256, 0, stream>>>(h, wbuf + 4 * DD,
        b1 + l * F_, nullptr, nullptr, mid, nullptr, nullptr, MTOT, 4096, 1024, 1024);

    // x += mid @ w2^T + b2   (split-K=2 -> 256 blocks)
    gemm_bt<1><<<dim3(128, 1, 2), 256, 0, stream>>>(mid, wbuf + 4 * DD + FD,
        b2 + l * D_, nullptr, nullptr, x, nullptr, nullptr, MTOT, 1024, 4096, 2048);
  }
}